// Round 17
// baseline (337.069 us; speedup 1.0000x reference)
//
#include <hip/hip_runtime.h>
#include <hip/hip_bf16.h>
#include <math.h>

typedef short v8s __attribute__((ext_vector_type(8)));
typedef float v4f __attribute__((ext_vector_type(4)));
typedef unsigned int v4u __attribute__((ext_vector_type(4)));
typedef unsigned short us;
typedef unsigned int uu;

#define MFMA16(a,b,c) __builtin_amdgcn_mfma_f32_16x16x32_bf16((a),(b),(c),0,0,0)

// ---------------- workspace layout (fragment-linear, permuted-k) ----------
// Permutation (chunk t): slot (g,i) holds logical k = 32t + 16*(i>>2) + 4g + (i&3).
// Layer N's D registers repack in-lane into layer N+1's B-fragment.
#define W3F_ELEMS (7*13*512)
#define W2F_ELEMS (13*512)
#define W4F_ELEMS (14*512)
#define WALL_ELEMS (W3F_ELEMS + W2F_ELEMS + W4F_ELEMS)   // 60416 -> 120832 B
#define OFF_W3F 0
#define OFF_W2F (OFF_W3F + W3F_ELEMS*2)
#define OFF_W4F (OFF_W2F + W2F_ELEMS*2)
#define OFF_B2B (OFF_W4F + W4F_ELEMS*2)
#define OFF_B3B (OFF_B2B + 208*4)
#define OFF_B4B (OFF_B3B + 224*4)
#define OFF_W5B (OFF_B4B + 32*4)
#define OFF_W1P (OFF_W5B + 32*4)   // [96] f32: w1x[32] | w1y[32] | b1p[32]
#define OFF_X   (256*1024)         // x_u[B*64] f32 | x_i[B*64] f32 | fp16 tables
// constants staged to LDS: [b2 208 | b3 224 | b4 32 | w5 32 | w1p 96]
#define CB_ELEMS 592
#define CB_B3 208
#define CB_B4 432
#define CB_W5 464
#define CB_W1 496

__device__ __forceinline__ us f2bf(float f) {
    union { float f; unsigned int u; } v; v.f = f;
    unsigned int u = v.u + 0x7FFFu + ((v.u >> 16) & 1u);   // RNE
    return (us)(u >> 16);
}
__device__ __forceinline__ uu pack2bf(float a, float b) {
    union { __hip_bfloat162 v; uu u; } cv;
    cv.v.x = __float2bfloat16(a);
    cv.v.y = __float2bfloat16(b);
    return cv.u;
}
__device__ __forceinline__ us f2h(float f) {
    _Float16 h = (_Float16)f;                              // RNE
    return *(us*)&h;
}

// ---------------- prep+conv: weights->bf16 frags, embeddings->fp16 --------
__global__ void prep_conv_kernel(
    const float* __restrict__ w1, const float* __restrict__ b1,
    const float* __restrict__ w2, const float* __restrict__ w3,
    const float* __restrict__ w4, const float* __restrict__ b2,
    const float* __restrict__ b3, const float* __restrict__ b4,
    const float* __restrict__ w5, char* __restrict__ ws,
    const float* __restrict__ uemb, const float* __restrict__ iemb,
    _Float16* __restrict__ ue16, _Float16* __restrict__ ie16,
    int nu64, int ni64)
{
    us* w3f = (us*)(ws + OFF_W3F);
    us* w2f = (us*)(ws + OFF_W2F);
    us* w4f = (us*)(ws + OFF_W4F);
    float* b2b = (float*)(ws + OFF_B2B);
    float* b3b = (float*)(ws + OFF_B3B);
    float* b4b = (float*)(ws + OFF_B4B);
    float* w5b = (float*)(ws + OFF_W5B);
    float* w1p = (float*)(ws + OFF_W1P);

    const int gid = blockIdx.x * blockDim.x + threadIdx.x;
    const int stride = gridDim.x * blockDim.x;

    // ---- embedding tables f32 -> fp16, 4-wide (counts are multiples of 64) -
    for (int i = gid*4; i < nu64; i += stride*4) {
        float4 v = *(const float4*)(uemb + i);
        ushort4 o = { f2h(v.x), f2h(v.y), f2h(v.z), f2h(v.w) };
        *(ushort4*)((us*)ue16 + i) = o;
    }
    for (int i = gid*4; i < ni64; i += stride*4) {
        float4 v = *(const float4*)(iemb + i);
        ushort4 o = { f2h(v.x), f2h(v.y), f2h(v.z), f2h(v.w) };
        *(ushort4*)((us*)ie16 + i) = o;
    }

    // ---- weight fragment prep ---------------------------------------------
    for (int idx = gid; idx < W3F_ELEMS; idx += stride) {
        int i = idx & 7, lane = (idx >> 3) & 63, f = idx >> 9;
        int nt3 = f % 13, t = f / 13;
        int cc = lane & 15, gg = lane >> 4;
        int j = 16*nt3 + cc;
        int k = 32*t + 16*(i >> 2) + 4*gg + (i & 3);    // permuted-k
        w3f[idx] = f2bf((j < 200 && k < 200) ? w3[j*200 + k] : 0.f);
    }
    for (int idx = gid; idx < W2F_ELEMS; idx += stride) {
        int i = idx & 7, lane = (idx >> 3) & 63, nt = idx >> 9;
        int j = 16*nt + (lane & 15), k = 8*(lane >> 4) + i;   // standard k
        w2f[idx] = f2bf((j < 200 && k < 20) ? w2[j*20 + k] : 0.f);
    }
    for (int idx = gid; idx < W4F_ELEMS; idx += stride) {
        int i = idx & 7, lane = (idx >> 3) & 63, f = idx >> 9;
        int t = f >> 1, jt = f & 1;
        int cc = lane & 15, gg = lane >> 4;
        int j = 16*jt + cc;
        int k = 32*t + 16*(i >> 2) + 4*gg + (i & 3);    // permuted-k
        w4f[idx] = f2bf((j < 20 && k < 200) ? w4[j*200 + k] : 0.f);
    }
    for (int i = gid; i < 208; i += stride) b2b[i] = (i < 200) ? b2[i] : 0.f;
    for (int i = gid; i < 224; i += stride) b3b[i] = (i < 200) ? b3[i] : 0.f;
    for (int i = gid; i < 32;  i += stride) b4b[i] = (i < 20) ? b4[i] : 0.f;
    for (int i = gid; i < 32;  i += stride) w5b[i] = (i < 20) ? w5[i] : 0.f;
    for (int i = gid; i < 96;  i += stride) {
        int q = i >> 5, r = i & 31;
        float v = 0.f;
        if (r < 20) v = (q == 0) ? w1[2*r] : (q == 1) ? w1[2*r + 1] : b1[r];
        w1p[i] = v;
    }
}

// ---------------- gather kernel: memory-regime, fp16 rows ------------------
__global__ __launch_bounds__(256, 8) void gather_kernel(
    const int* __restrict__ user_idxs, const int* __restrict__ item_idxs,
    const int* __restrict__ uidx, const int* __restrict__ iidx,
    const _Float16* __restrict__ ue16, const _Float16* __restrict__ ie16,
    float* __restrict__ xu, float* __restrict__ xi, int B)
{
    const int tid  = (int)threadIdx.x;
    const int lane = tid & 63;
    const int task = (int)blockIdx.x * 4 + (tid >> 6);
    if (task >= 2*B) return;
    const int b = task >> 1;
    const bool isItem = task & 1;

    const int* nrow = isItem ? (iidx + (size_t)item_idxs[b]*100)
                             : (uidx + (size_t)user_idxs[b]*100);
    const _Float16* emb = isItem ? ie16 : ue16;

    float a0=0.f,a1=0.f,a2=0.f,a3=0.f,a4=0.f,a5=0.f,a6=0.f,a7=0.f;
    #pragma unroll 2
    for (int k = 0; k < 96; k += 16) {            // 6 rounds x 16 rows
        int4 i0 = *(const int4*)(nrow + k);       // wave-uniform -> s_load
        int4 i1 = *(const int4*)(nrow + k + 4);
        int4 i2 = *(const int4*)(nrow + k + 8);
        int4 i3 = *(const int4*)(nrow + k + 12);
        a0 += (float)emb[(size_t)i0.x*64 + lane]; // coalesced 128-B rows
        a1 += (float)emb[(size_t)i0.y*64 + lane];
        a2 += (float)emb[(size_t)i0.z*64 + lane];
        a3 += (float)emb[(size_t)i0.w*64 + lane];
        a4 += (float)emb[(size_t)i1.x*64 + lane];
        a5 += (float)emb[(size_t)i1.y*64 + lane];
        a6 += (float)emb[(size_t)i1.z*64 + lane];
        a7 += (float)emb[(size_t)i1.w*64 + lane];
        a0 += (float)emb[(size_t)i2.x*64 + lane];
        a1 += (float)emb[(size_t)i2.y*64 + lane];
        a2 += (float)emb[(size_t)i2.z*64 + lane];
        a3 += (float)emb[(size_t)i2.w*64 + lane];
        a4 += (float)emb[(size_t)i3.x*64 + lane];
        a5 += (float)emb[(size_t)i3.y*64 + lane];
        a6 += (float)emb[(size_t)i3.z*64 + lane];
        a7 += (float)emb[(size_t)i3.w*64 + lane];
    }
    int4 it = *(const int4*)(nrow + 96);           // rows 96..99
    a0 += (float)emb[(size_t)it.x*64 + lane];
    a1 += (float)emb[(size_t)it.y*64 + lane];
    a2 += (float)emb[(size_t)it.z*64 + lane];
    a3 += (float)emb[(size_t)it.w*64 + lane];

    float s = ((a0+a4)+(a1+a5)) + ((a2+a6)+(a3+a7));
    (isItem ? xi : xu)[(size_t)b*64 + lane] = s;   // coalesced 256-B store
}

// ---- layer 1 (2->20) for pass P (e = 32P + 16m + c), into B-frag regs -----
template <int P>
__device__ __forceinline__ void make_b1f2(float su, float si, int c, int g,
                                          const float* __restrict__ w1p,
                                          v4u b1f[2])
{
    const v4f wx0 = *(const v4f*)(w1p + 8*g);
    const v4f wx1 = *(const v4f*)(w1p + 8*g + 4);
    const v4f wy0 = *(const v4f*)(w1p + 32 + 8*g);
    const v4f wy1 = *(const v4f*)(w1p + 32 + 8*g + 4);
    const v4f wb0 = *(const v4f*)(w1p + 64 + 8*g);
    const v4f wb1 = *(const v4f*)(w1p + 64 + 8*g + 4);
    #pragma unroll
    for (int m = 0; m < 2; ++m) {
        const float xu = __shfl(su, 32*P + 16*m + c);
        const float xv = __shfl(si, 32*P + 16*m + c);
        float h0 = fmaxf(fmaf(xu, wx0[0], fmaf(xv, wy0[0], wb0[0])), 0.f);
        float h1 = fmaxf(fmaf(xu, wx0[1], fmaf(xv, wy0[1], wb0[1])), 0.f);
        float h2 = fmaxf(fmaf(xu, wx0[2], fmaf(xv, wy0[2], wb0[2])), 0.f);
        float h3 = fmaxf(fmaf(xu, wx0[3], fmaf(xv, wy0[3], wb0[3])), 0.f);
        float h4 = fmaxf(fmaf(xu, wx1[0], fmaf(xv, wy1[0], wb1[0])), 0.f);
        float h5 = fmaxf(fmaf(xu, wx1[1], fmaf(xv, wy1[1], wb1[1])), 0.f);
        float h6 = fmaxf(fmaf(xu, wx1[2], fmaf(xv, wy1[2], wb1[2])), 0.f);
        float h7 = fmaxf(fmaf(xu, wx1[3], fmaf(xv, wy1[3], wb1[3])), 0.f);
        b1f[m] = (v4u){ pack2bf(h0,h1), pack2bf(h2,h3),
                        pack2bf(h4,h5), pack2bf(h6,h7) };
    }
}

// ---- layers 2-5 for one 32-row pass (m=2), layer3/4 fused by nt-pair ------
// Register budget: b2f 56 + acc3 16 + acc4 16 + b1f 8 + transients ~50 < 170.
__device__ __forceinline__ float mlp_pass2(
    const v4u b1f[2],
    const us* __restrict__ w3l, const us* __restrict__ w2l,
    const us* __restrict__ w4l, const float* __restrict__ cbuf,
    const int lane, const int g)
{
    const v8s bb0 = __builtin_bit_cast(v8s, b1f[0]);
    const v8s bb1 = __builtin_bit_cast(v8s, b1f[1]);

    // ---- Layer 2 (20->200): paired nt, bias as C-in ------------------------
    v4u b2f[2][7];
    __builtin_amdgcn_s_setprio(1);
    #pragma unroll
    for (int t = 0; t < 6; ++t) {
        v8s afa = *(const v8s*)(w2l + ((2*t)*64   + lane)*8);
        v8s afb = *(const v8s*)(w2l + ((2*t+1)*64 + lane)*8);
        v4f bva = *(const v4f*)(cbuf + 32*t + 4*g);
        v4f bvb = *(const v4f*)(cbuf + 32*t + 16 + 4*g);
        v4f aa0 = MFMA16(afa, bb0, bva);
        v4f aa1 = MFMA16(afa, bb1, bva);
        v4f ab0 = MFMA16(afb, bb0, bvb);
        v4f ab1 = MFMA16(afb, bb1, bvb);
        b2f[0][t] = (v4u){ pack2bf(fmaxf(aa0[0],0.f), fmaxf(aa0[1],0.f)),
                           pack2bf(fmaxf(aa0[2],0.f), fmaxf(aa0[3],0.f)),
                           pack2bf(fmaxf(ab0[0],0.f), fmaxf(ab0[1],0.f)),
                           pack2bf(fmaxf(ab0[2],0.f), fmaxf(ab0[3],0.f)) };
        b2f[1][t] = (v4u){ pack2bf(fmaxf(aa1[0],0.f), fmaxf(aa1[1],0.f)),
                           pack2bf(fmaxf(aa1[2],0.f), fmaxf(aa1[3],0.f)),
                           pack2bf(fmaxf(ab1[0],0.f), fmaxf(ab1[1],0.f)),
                           pack2bf(fmaxf(ab1[2],0.f), fmaxf(ab1[3],0.f)) };
    }
    {   // t = 6: nt = 12 only; upper k-half zero (pad)
        v8s afa = *(const v8s*)(w2l + (12*64 + lane)*8);
        v4f bva = *(const v4f*)(cbuf + 192 + 4*g);
        v4f aa0 = MFMA16(afa, bb0, bva);
        v4f aa1 = MFMA16(afa, bb1, bva);
        b2f[0][6] = (v4u){ pack2bf(fmaxf(aa0[0],0.f), fmaxf(aa0[1],0.f)),
                           pack2bf(fmaxf(aa0[2],0.f), fmaxf(aa0[3],0.f)), 0u, 0u };
        b2f[1][6] = (v4u){ pack2bf(fmaxf(aa1[0],0.f), fmaxf(aa1[1],0.f)),
                           pack2bf(fmaxf(aa1[2],0.f), fmaxf(aa1[3],0.f)), 0u, 0u };
    }
    __builtin_amdgcn_s_setprio(0);

    // ---- Layers 3+4 fused at nt-pair granularity ----------------------------
    v4f acc4[2][2];
    v4f bc0 = *(const v4f*)(cbuf + CB_B4 + 4*g);
    v4f bc1 = *(const v4f*)(cbuf + CB_B4 + 16 + 4*g);
    #pragma unroll
    for (int p = 0; p < 7; ++p) {
        v8s a40 = *(const v8s*)(w4l + ((2*p)*64   + lane)*8);
        v8s a41 = *(const v8s*)(w4l + ((2*p+1)*64 + lane)*8);

        v4f acc3[2][2];
        __builtin_amdgcn_s_setprio(1);
        {   // ksc = 0, bias as C-in
            v8s af0 = *(const v8s*)(w3l + ((2*p)*64 + lane)*8);
            v4f bv0 = *(const v4f*)(cbuf + CB_B3 + 16*(2*p) + 4*g);
            acc3[0][0] = MFMA16(af0, __builtin_bit_cast(v8s, b2f[0][0]), bv0);
            acc3[1][0] = MFMA16(af0, __builtin_bit_cast(v8s, b2f[1][0]), bv0);
            if (p < 6) {
                v8s af1 = *(const v8s*)(w3l + ((2*p+1)*64 + lane)*8);
                v4f bv1 = *(const v4f*)(cbuf + CB_B3 + 16*(2*p+1) + 4*g);
                acc3[0][1] = MFMA16(af1, __builtin_bit_cast(v8s, b2f[0][0]), bv1);
                acc3[1][1] = MFMA16(af1, __builtin_bit_cast(v8s, b2f[1][0]), bv1);
            }
        }
        #pragma unroll
        for (int ksc = 1; ksc < 7; ++ksc) {
            v8s af0 = *(const v8s*)(w3l + ((ksc*13 + 2*p)*64 + lane)*8);
            acc3[0][0] = MFMA16(af0, __builtin_bit_cast(v8s, b2f[0][ksc]), acc3[0][0]);
            acc3[1][0] = MFMA16(af0, __builtin_bit_cast(v8s, b2f[1][ksc]), acc3[1][0]);
            if (p < 6) {
                v8s af1 = *(const v8s*)(w3l + ((ksc*13 + 2*p+1)*64 + lane)*8);
                acc3[0][1] = MFMA16(af1, __builtin_bit_cast(v8s, b2f[0][ksc]), acc3[0][1]);
                acc3[1][1] = MFMA16(af1, __builtin_bit_cast(v8s, b2f[1][ksc]), acc3[1][1]);
            }
        }
        __builtin_amdgcn_s_setprio(0);
        // repack + layer-4 MFMAs (acc3 dies here)
        #pragma unroll
        for (int m = 0; m < 2; ++m) {
            v4u bfu;
            if (p < 6) {
                bfu = (v4u){
                    pack2bf(fmaxf(acc3[m][0][0],0.f), fmaxf(acc3[m][0][1],0.f)),
                    pack2bf(fmaxf(acc3[m][0][2],0.f), fmaxf(acc3[m][0][3],0.f)),
                    pack2bf(fmaxf(acc3[m][1][0],0.f), fmaxf(acc3[m][1][1],0.f)),
                    pack2bf(fmaxf(acc3[m][1][2],0.f), fmaxf(acc3[m][1][3],0.f)) };
            } else {
                bfu = (v4u){
                    pack2bf(fmaxf(acc3[m][0][0],0.f), fmaxf(acc3[m][0][1],0.f)),
                    pack2bf(fmaxf(acc3[m][0][2],0.f), fmaxf(acc3[m][0][3],0.f)),
                    0u, 0u };
            }
            v8s bb = __builtin_bit_cast(v8s, bfu);
            acc4[m][0] = MFMA16(a40, bb, (p == 0) ? bc0 : acc4[m][0]);
            acc4[m][1] = MFMA16(a41, bb, (p == 0) ? bc1 : acc4[m][1]);
        }
    }

    // ---- Layer 5 (20->1) dot: per-lane partial ------------------------------
    v4f w5lo = *(const v4f*)(cbuf + CB_W5 + 4*g);
    v4f w5hi = *(const v4f*)(cbuf + CB_W5 + 16 + 4*g);
    float s = 0.f;
    #pragma unroll
    for (int m = 0; m < 2; ++m) {
        #pragma unroll
        for (int q = 0; q < 4; ++q) {
            float h0 = fmaxf(acc4[m][0][q], 0.f);   // bias already in acc
            float h1 = fmaxf(acc4[m][1][q], 0.f);
            s = fmaf(h0, w5lo[q], fmaf(h1, w5hi[q], s));
        }
    }
    return s;
}

// ---------------- MLP kernel: m=2 two-pass at 3 waves/SIMD -----------------
// Persistent: 256 blocks x 12 waves (768 thr) -> 3 waves/SIMD (reg cap 170;
// pass state ~140 fits -- spill sentinel: WRITE_SIZE). Weights + constants
// in LDS. Wave = independent worker: one batch row per iteration in TWO
// 32-e passes; sched_barrier(0) between passes keeps only one pass's state
// live (r11 lesson). x prefetch in pass-1 region.
__global__ __launch_bounds__(768, 3) void mlp_kernel(
    const float* __restrict__ xu, const float* __restrict__ xi,
    const float* __restrict__ b5p, const char* __restrict__ ws,
    float* __restrict__ out, int B, int NIT)
{
    __shared__ us wall[WALL_ELEMS];                // 120832 B : w3f | w2f | w4f
    __shared__ __align__(16) float cbuf[CB_ELEMS]; //   2368 B : biases + w1p

    const int tid  = (int)threadIdx.x;
    const int lane = tid & 63;
    const int wv   = __builtin_amdgcn_readfirstlane(tid >> 6);   // 0..11
    const int c = lane & 15;
    const int g = lane >> 4;
    const int wstep = (int)gridDim.x * 12;         // batch rows per iteration

    // ---- stage weights + constants to LDS once ----------------------------
    {
        const us* src = (const us*)(ws + OFF_W3F);
        for (int s = tid; s < WALL_ELEMS/8; s += 768)
            *(v8s*)(wall + s*8) = *(const v8s*)(src + s*8);
        const float* csrc = (const float*)(ws + OFF_B2B);
        for (int s = tid; s < CB_ELEMS; s += 768)
            cbuf[s] = csrc[s];
    }
    const us* w3l = wall;
    const us* w2l = wall + W3F_ELEMS;
    const us* w4l = wall + W3F_ELEMS + W2F_ELEMS;
    const float b5v = b5p[0];

    int b = (int)blockIdx.x*12 + wv;
    int bc = (b < B) ? b : (B - 1);
    float su = xu[(size_t)bc*64 + lane];
    float si = xi[(size_t)bc*64 + lane];
    __syncthreads();                               // weights staged (only barrier)

    #pragma unroll 1
    for (int it = 0; it < NIT; ++it) {
        const int nb = b + wstep;
        const int nbc = (nb < B) ? nb : (B - 1);
        const bool more = (it + 1 < NIT);

        // ---- pass 0 (e rows 0..31) ------------------------------------------
        v4u b1f[2];
        make_b1f2<0>(su, si, c, g, cbuf + CB_W1, b1f);
        float s = mlp_pass2(b1f, w3l, w2l, w4l, cbuf, lane, g);

        __builtin_amdgcn_sched_barrier(0);   // fence: pass-0 state dies here

        // ---- pass 1 (e rows 32..63); prefetch next x inside this region -----
        float nsu = 0.f, nsi = 0.f;
        if (more) {
            nsu = xu[(size_t)nbc*64 + lane];       // 2 coalesced loads,
            nsi = xi[(size_t)nbc*64 + lane];       // hidden under pass-1 MFMAs
        }
        make_b1f2<1>(su, si, c, g, cbuf + CB_W1, b1f);   // su/si die here
        s += mlp_pass2(b1f, w3l, w2l, w4l, cbuf, lane, g);

        __builtin_amdgcn_sched_barrier(0);   // fence: pass-1 state dies here

        // ---- mean over E=64 + sigmoid; single wave-level reduce --------------
        #pragma unroll
        for (int off = 1; off < 64; off <<= 1) s += __shfl_xor(s, off);
        if (lane == 0 && b < B)
            out[b] = 1.0f / (1.0f + expf(-(s * (1.0f / 64.0f) + b5v)));

        su = nsu; si = nsi; b = nb;
    }
}

extern "C" void kernel_launch(void* const* d_in, const int* in_sizes, int n_in,
                              void* d_out, int out_size, void* d_ws, size_t ws_size,
                              hipStream_t stream) {
    const int*   user_idxs = (const int*)d_in[0];
    const int*   item_idxs = (const int*)d_in[1];
    const int*   uidx      = (const int*)d_in[2];
    const int*   iidx      = (const int*)d_in[3];
    const float* uemb      = (const float*)d_in[4];
    const float* iemb      = (const float*)d_in[5];
    const float* w1 = (const float*)d_in[6];
    const float* b1 = (const float*)d_in[7];
    const float* w2 = (const float*)d_in[8];
    const float* b2 = (const float*)d_in[9];
    const float* w3 = (const float*)d_in[10];
    const float* b3 = (const float*)d_in[11];
    const float* w4 = (const float*)d_in[12];
    const float* b4 = (const float*)d_in[13];
    const float* w5 = (const float*)d_in[14];
    const float* b5 = (const float*)d_in[15];
    float* out = (float*)d_out;
    char* ws = (char*)d_ws;

    const int B    = in_sizes[0];
    const int nu64 = in_sizes[4];   // N_USERS * 64
    const int ni64 = in_sizes[5];   // N_ITEMS * 64

    float* xu = (float*)(ws + OFF_X);
    float* xi = xu + (size_t)B * 64;
    _Float16* ue16 = (_Float16*)(ws + OFF_X + (size_t)2 * B * 64 * 4);
    _Float16* ie16 = ue16 + nu64;

    hipLaunchKernelGGL(prep_conv_kernel, dim3(1024), dim3(256), 0, stream,
                       w1, b1, w2, w3, w4, b2, b3, b4, w5, ws,
                       uemb, iemb, ue16, ie16, nu64, ni64);

    const int ntask = 2 * B;                       // (b, table) wave-tasks
    hipLaunchKernelGGL(gather_kernel, dim3((ntask + 3) / 4), dim3(256), 0, stream,
                       user_idxs, item_idxs, uidx, iidx, ue16, ie16, xu, xi, B);

    const int GRID = 256;
    const int rows_per_iter = GRID * 12;
    const int NIT = (B + rows_per_iter - 1) / rows_per_iter;
    hipLaunchKernelGGL(mlp_kernel, dim3(GRID), dim3(768), 0, stream,
                       xu, xi, b5, ws, out, B, NIT);
}

// Round 18
// 331.203 us; speedup vs baseline: 1.0177x; 1.0177x over previous
//
#include <hip/hip_runtime.h>
#include <hip/hip_bf16.h>
#include <math.h>

typedef short v8s __attribute__((ext_vector_type(8)));
typedef float v4f __attribute__((ext_vector_type(4)));
typedef unsigned int v4u __attribute__((ext_vector_type(4)));
typedef unsigned short us;
typedef unsigned int uu;

#define MFMA16(a,b,c) __builtin_amdgcn_mfma_f32_16x16x32_bf16((a),(b),(c),0,0,0)

// ---------------- workspace layout (fragment-linear, permuted-k) ----------
// Permutation (chunk t): slot (g,i) holds logical k = 32t + 16*(i>>2) + 4g + (i&3).
// Layer N's D registers repack in-lane into layer N+1's B-fragment.
#define W3F_ELEMS (7*13*512)
#define W2F_ELEMS (13*512)
#define W4F_ELEMS (14*512)
#define WALL_ELEMS (W3F_ELEMS + W2F_ELEMS + W4F_ELEMS)   // 60416 -> 120832 B
#define OFF_W3F 0
#define OFF_W2F (OFF_W3F + W3F_ELEMS*2)
#define OFF_W4F (OFF_W2F + W2F_ELEMS*2)
#define OFF_B2B (OFF_W4F + W4F_ELEMS*2)
#define OFF_B3B (OFF_B2B + 208*4)
#define OFF_B4B (OFF_B3B + 224*4)
#define OFF_W5B (OFF_B4B + 32*4)
#define OFF_W1P (OFF_W5B + 32*4)   // [96] f32: w1x[32] | w1y[32] | b1p[32]
#define OFF_X   (256*1024)         // x_u[B*64] f32 | x_i[B*64] f32 | fp16 tables
// constants staged to LDS: [b2 208 | b3 224 | b4 32 | w5 32 | w1p 96]
#define CB_ELEMS 592
#define CB_B3 208
#define CB_B4 432
#define CB_W5 464
#define CB_W1 496

__device__ __forceinline__ us f2bf(float f) {
    union { float f; unsigned int u; } v; v.f = f;
    unsigned int u = v.u + 0x7FFFu + ((v.u >> 16) & 1u);   // RNE
    return (us)(u >> 16);
}
// single v_cvt_pk_bf16_f32 (memcpy is layout-safe where bit_cast was rejected)
__device__ __forceinline__ uu pack2bf(float a, float b) {
    __hip_bfloat162 h = __float22bfloat162_rn(float2{a, b});
    uu r; __builtin_memcpy(&r, &h, 4); return r;
}
__device__ __forceinline__ us f2h(float f) {
    _Float16 h = (_Float16)f;                              // RNE
    return *(us*)&h;
}

// ---------------- prep+conv: weights->bf16 frags, embeddings->fp16 --------
__global__ void prep_conv_kernel(
    const float* __restrict__ w1, const float* __restrict__ b1,
    const float* __restrict__ w2, const float* __restrict__ w3,
    const float* __restrict__ w4, const float* __restrict__ b2,
    const float* __restrict__ b3, const float* __restrict__ b4,
    const float* __restrict__ w5, char* __restrict__ ws,
    const float* __restrict__ uemb, const float* __restrict__ iemb,
    _Float16* __restrict__ ue16, _Float16* __restrict__ ie16,
    int nu64, int ni64)
{
    us* w3f = (us*)(ws + OFF_W3F);
    us* w2f = (us*)(ws + OFF_W2F);
    us* w4f = (us*)(ws + OFF_W4F);
    float* b2b = (float*)(ws + OFF_B2B);
    float* b3b = (float*)(ws + OFF_B3B);
    float* b4b = (float*)(ws + OFF_B4B);
    float* w5b = (float*)(ws + OFF_W5B);
    float* w1p = (float*)(ws + OFF_W1P);

    const int gid = blockIdx.x * blockDim.x + threadIdx.x;
    const int stride = gridDim.x * blockDim.x;

    // ---- embedding tables f32 -> fp16, 4-wide (counts are multiples of 64) -
    for (int i = gid*4; i < nu64; i += stride*4) {
        float4 v = *(const float4*)(uemb + i);
        ushort4 o = { f2h(v.x), f2h(v.y), f2h(v.z), f2h(v.w) };
        *(ushort4*)((us*)ue16 + i) = o;
    }
    for (int i = gid*4; i < ni64; i += stride*4) {
        float4 v = *(const float4*)(iemb + i);
        ushort4 o = { f2h(v.x), f2h(v.y), f2h(v.z), f2h(v.w) };
        *(ushort4*)((us*)ie16 + i) = o;
    }

    // ---- weight fragment prep ---------------------------------------------
    for (int idx = gid; idx < W3F_ELEMS; idx += stride) {
        int i = idx & 7, lane = (idx >> 3) & 63, f = idx >> 9;
        int nt3 = f % 13, t = f / 13;
        int cc = lane & 15, gg = lane >> 4;
        int j = 16*nt3 + cc;
        int k = 32*t + 16*(i >> 2) + 4*gg + (i & 3);    // permuted-k
        w3f[idx] = f2bf((j < 200 && k < 200) ? w3[j*200 + k] : 0.f);
    }
    for (int idx = gid; idx < W2F_ELEMS; idx += stride) {
        int i = idx & 7, lane = (idx >> 3) & 63, nt = idx >> 9;
        int j = 16*nt + (lane & 15), k = 8*(lane >> 4) + i;   // standard k
        w2f[idx] = f2bf((j < 200 && k < 20) ? w2[j*20 + k] : 0.f);
    }
    for (int idx = gid; idx < W4F_ELEMS; idx += stride) {
        int i = idx & 7, lane = (idx >> 3) & 63, f = idx >> 9;
        int t = f >> 1, jt = f & 1;
        int cc = lane & 15, gg = lane >> 4;
        int j = 16*jt + cc;
        int k = 32*t + 16*(i >> 2) + 4*gg + (i & 3);    // permuted-k
        w4f[idx] = f2bf((j < 20 && k < 200) ? w4[j*200 + k] : 0.f);
    }
    for (int i = gid; i < 208; i += stride) b2b[i] = (i < 200) ? b2[i] : 0.f;
    for (int i = gid; i < 224; i += stride) b3b[i] = (i < 200) ? b3[i] : 0.f;
    for (int i = gid; i < 32;  i += stride) b4b[i] = (i < 20) ? b4[i] : 0.f;
    for (int i = gid; i < 32;  i += stride) w5b[i] = (i < 20) ? w5[i] : 0.f;
    for (int i = gid; i < 96;  i += stride) {
        int q = i >> 5, r = i & 31;
        float v = 0.f;
        if (r < 20) v = (q == 0) ? w1[2*r] : (q == 1) ? w1[2*r + 1] : b1[r];
        w1p[i] = v;
    }
}

// ---------------- gather kernel: memory-regime, fp16 rows ------------------
__global__ __launch_bounds__(256, 8) void gather_kernel(
    const int* __restrict__ user_idxs, const int* __restrict__ item_idxs,
    const int* __restrict__ uidx, const int* __restrict__ iidx,
    const _Float16* __restrict__ ue16, const _Float16* __restrict__ ie16,
    float* __restrict__ xu, float* __restrict__ xi, int B)
{
    const int tid  = (int)threadIdx.x;
    const int lane = tid & 63;
    const int task = (int)blockIdx.x * 4 + (tid >> 6);
    if (task >= 2*B) return;
    const int b = task >> 1;
    const bool isItem = task & 1;

    const int* nrow = isItem ? (iidx + (size_t)item_idxs[b]*100)
                             : (uidx + (size_t)user_idxs[b]*100);
    const _Float16* emb = isItem ? ie16 : ue16;

    float a0=0.f,a1=0.f,a2=0.f,a3=0.f,a4=0.f,a5=0.f,a6=0.f,a7=0.f;
    #pragma unroll 2
    for (int k = 0; k < 96; k += 16) {            // 6 rounds x 16 rows
        int4 i0 = *(const int4*)(nrow + k);       // wave-uniform -> s_load
        int4 i1 = *(const int4*)(nrow + k + 4);
        int4 i2 = *(const int4*)(nrow + k + 8);
        int4 i3 = *(const int4*)(nrow + k + 12);
        a0 += (float)emb[(size_t)i0.x*64 + lane]; // coalesced 128-B rows
        a1 += (float)emb[(size_t)i0.y*64 + lane];
        a2 += (float)emb[(size_t)i0.z*64 + lane];
        a3 += (float)emb[(size_t)i0.w*64 + lane];
        a4 += (float)emb[(size_t)i1.x*64 + lane];
        a5 += (float)emb[(size_t)i1.y*64 + lane];
        a6 += (float)emb[(size_t)i1.z*64 + lane];
        a7 += (float)emb[(size_t)i1.w*64 + lane];
        a0 += (float)emb[(size_t)i2.x*64 + lane];
        a1 += (float)emb[(size_t)i2.y*64 + lane];
        a2 += (float)emb[(size_t)i2.z*64 + lane];
        a3 += (float)emb[(size_t)i2.w*64 + lane];
        a4 += (float)emb[(size_t)i3.x*64 + lane];
        a5 += (float)emb[(size_t)i3.y*64 + lane];
        a6 += (float)emb[(size_t)i3.z*64 + lane];
        a7 += (float)emb[(size_t)i3.w*64 + lane];
    }
    int4 it = *(const int4*)(nrow + 96);           // rows 96..99
    a0 += (float)emb[(size_t)it.x*64 + lane];
    a1 += (float)emb[(size_t)it.y*64 + lane];
    a2 += (float)emb[(size_t)it.z*64 + lane];
    a3 += (float)emb[(size_t)it.w*64 + lane];

    float s = ((a0+a4)+(a1+a5)) + ((a2+a6)+(a3+a7));
    (isItem ? xi : xu)[(size_t)b*64 + lane] = s;   // coalesced 256-B store
}

// ---- layer 1 (2->20) for pass P (e = 32P + 16m + c), into B-frag regs -----
template <int P>
__device__ __forceinline__ void make_b1f2(float su, float si, int c, int g,
                                          const float* __restrict__ w1p,
                                          v4u b1f[2])
{
    const v4f wx0 = *(const v4f*)(w1p + 8*g);
    const v4f wx1 = *(const v4f*)(w1p + 8*g + 4);
    const v4f wy0 = *(const v4f*)(w1p + 32 + 8*g);
    const v4f wy1 = *(const v4f*)(w1p + 32 + 8*g + 4);
    const v4f wb0 = *(const v4f*)(w1p + 64 + 8*g);
    const v4f wb1 = *(const v4f*)(w1p + 64 + 8*g + 4);
    #pragma unroll
    for (int m = 0; m < 2; ++m) {
        const float xu = __shfl(su, 32*P + 16*m + c);
        const float xv = __shfl(si, 32*P + 16*m + c);
        float h0 = fmaxf(fmaf(xu, wx0[0], fmaf(xv, wy0[0], wb0[0])), 0.f);
        float h1 = fmaxf(fmaf(xu, wx0[1], fmaf(xv, wy0[1], wb0[1])), 0.f);
        float h2 = fmaxf(fmaf(xu, wx0[2], fmaf(xv, wy0[2], wb0[2])), 0.f);
        float h3 = fmaxf(fmaf(xu, wx0[3], fmaf(xv, wy0[3], wb0[3])), 0.f);
        float h4 = fmaxf(fmaf(xu, wx1[0], fmaf(xv, wy1[0], wb1[0])), 0.f);
        float h5 = fmaxf(fmaf(xu, wx1[1], fmaf(xv, wy1[1], wb1[1])), 0.f);
        float h6 = fmaxf(fmaf(xu, wx1[2], fmaf(xv, wy1[2], wb1[2])), 0.f);
        float h7 = fmaxf(fmaf(xu, wx1[3], fmaf(xv, wy1[3], wb1[3])), 0.f);
        b1f[m] = (v4u){ pack2bf(h0,h1), pack2bf(h2,h3),
                        pack2bf(h4,h5), pack2bf(h6,h7) };
    }
}

// ---- layers 2-5 for one 32-row pass (m=2), layer3/4 fused by nt-pair ------
__device__ __forceinline__ float mlp_pass2(
    const v4u b1f[2],
    const us* __restrict__ w3l, const us* __restrict__ w2l,
    const us* __restrict__ w4l, const float* __restrict__ cbuf,
    const int lane, const int g)
{
    const v8s bb0 = __builtin_bit_cast(v8s, b1f[0]);
    const v8s bb1 = __builtin_bit_cast(v8s, b1f[1]);

    // ---- Layer 2 (20->200): paired nt, bias as C-in ------------------------
    v4u b2f[2][7];
    __builtin_amdgcn_s_setprio(1);
    #pragma unroll
    for (int t = 0; t < 6; ++t) {
        v8s afa = *(const v8s*)(w2l + ((2*t)*64   + lane)*8);
        v8s afb = *(const v8s*)(w2l + ((2*t+1)*64 + lane)*8);
        v4f bva = *(const v4f*)(cbuf + 32*t + 4*g);
        v4f bvb = *(const v4f*)(cbuf + 32*t + 16 + 4*g);
        v4f aa0 = MFMA16(afa, bb0, bva);
        v4f aa1 = MFMA16(afa, bb1, bva);
        v4f ab0 = MFMA16(afb, bb0, bvb);
        v4f ab1 = MFMA16(afb, bb1, bvb);
        b2f[0][t] = (v4u){ pack2bf(fmaxf(aa0[0],0.f), fmaxf(aa0[1],0.f)),
                           pack2bf(fmaxf(aa0[2],0.f), fmaxf(aa0[3],0.f)),
                           pack2bf(fmaxf(ab0[0],0.f), fmaxf(ab0[1],0.f)),
                           pack2bf(fmaxf(ab0[2],0.f), fmaxf(ab0[3],0.f)) };
        b2f[1][t] = (v4u){ pack2bf(fmaxf(aa1[0],0.f), fmaxf(aa1[1],0.f)),
                           pack2bf(fmaxf(aa1[2],0.f), fmaxf(aa1[3],0.f)),
                           pack2bf(fmaxf(ab1[0],0.f), fmaxf(ab1[1],0.f)),
                           pack2bf(fmaxf(ab1[2],0.f), fmaxf(ab1[3],0.f)) };
    }
    {   // t = 6: nt = 12 only; upper k-half zero (pad)
        v8s afa = *(const v8s*)(w2l + (12*64 + lane)*8);
        v4f bva = *(const v4f*)(cbuf + 192 + 4*g);
        v4f aa0 = MFMA16(afa, bb0, bva);
        v4f aa1 = MFMA16(afa, bb1, bva);
        b2f[0][6] = (v4u){ pack2bf(fmaxf(aa0[0],0.f), fmaxf(aa0[1],0.f)),
                           pack2bf(fmaxf(aa0[2],0.f), fmaxf(aa0[3],0.f)), 0u, 0u };
        b2f[1][6] = (v4u){ pack2bf(fmaxf(aa1[0],0.f), fmaxf(aa1[1],0.f)),
                           pack2bf(fmaxf(aa1[2],0.f), fmaxf(aa1[3],0.f)), 0u, 0u };
    }
    __builtin_amdgcn_s_setprio(0);

    // ---- Layers 3+4 fused at nt-pair granularity ----------------------------
    v4f acc4[2][2];
    v4f bc0 = *(const v4f*)(cbuf + CB_B4 + 4*g);
    v4f bc1 = *(const v4f*)(cbuf + CB_B4 + 16 + 4*g);
    #pragma unroll
    for (int p = 0; p < 7; ++p) {
        v8s a40 = *(const v8s*)(w4l + ((2*p)*64   + lane)*8);
        v8s a41 = *(const v8s*)(w4l + ((2*p+1)*64 + lane)*8);

        v4f acc3[2][2];
        __builtin_amdgcn_s_setprio(1);
        {   // ksc = 0, bias as C-in
            v8s af0 = *(const v8s*)(w3l + ((2*p)*64 + lane)*8);
            v4f bv0 = *(const v4f*)(cbuf + CB_B3 + 16*(2*p) + 4*g);
            acc3[0][0] = MFMA16(af0, __builtin_bit_cast(v8s, b2f[0][0]), bv0);
            acc3[1][0] = MFMA16(af0, __builtin_bit_cast(v8s, b2f[1][0]), bv0);
            if (p < 6) {
                v8s af1 = *(const v8s*)(w3l + ((2*p+1)*64 + lane)*8);
                v4f bv1 = *(const v4f*)(cbuf + CB_B3 + 16*(2*p+1) + 4*g);
                acc3[0][1] = MFMA16(af1, __builtin_bit_cast(v8s, b2f[0][0]), bv1);
                acc3[1][1] = MFMA16(af1, __builtin_bit_cast(v8s, b2f[1][0]), bv1);
            }
        }
        #pragma unroll
        for (int ksc = 1; ksc < 7; ++ksc) {
            v8s af0 = *(const v8s*)(w3l + ((ksc*13 + 2*p)*64 + lane)*8);
            acc3[0][0] = MFMA16(af0, __builtin_bit_cast(v8s, b2f[0][ksc]), acc3[0][0]);
            acc3[1][0] = MFMA16(af0, __builtin_bit_cast(v8s, b2f[1][ksc]), acc3[1][0]);
            if (p < 6) {
                v8s af1 = *(const v8s*)(w3l + ((ksc*13 + 2*p+1)*64 + lane)*8);
                acc3[0][1] = MFMA16(af1, __builtin_bit_cast(v8s, b2f[0][ksc]), acc3[0][1]);
                acc3[1][1] = MFMA16(af1, __builtin_bit_cast(v8s, b2f[1][ksc]), acc3[1][1]);
            }
        }
        __builtin_amdgcn_s_setprio(0);
        // repack + layer-4 MFMAs (acc3 dies here)
        #pragma unroll
        for (int m = 0; m < 2; ++m) {
            v4u bfu;
            if (p < 6) {
                bfu = (v4u){
                    pack2bf(fmaxf(acc3[m][0][0],0.f), fmaxf(acc3[m][0][1],0.f)),
                    pack2bf(fmaxf(acc3[m][0][2],0.f), fmaxf(acc3[m][0][3],0.f)),
                    pack2bf(fmaxf(acc3[m][1][0],0.f), fmaxf(acc3[m][1][1],0.f)),
                    pack2bf(fmaxf(acc3[m][1][2],0.f), fmaxf(acc3[m][1][3],0.f)) };
            } else {
                bfu = (v4u){
                    pack2bf(fmaxf(acc3[m][0][0],0.f), fmaxf(acc3[m][0][1],0.f)),
                    pack2bf(fmaxf(acc3[m][0][2],0.f), fmaxf(acc3[m][0][3],0.f)),
                    0u, 0u };
            }
            v8s bb = __builtin_bit_cast(v8s, bfu);
            acc4[m][0] = MFMA16(a40, bb, (p == 0) ? bc0 : acc4[m][0]);
            acc4[m][1] = MFMA16(a41, bb, (p == 0) ? bc1 : acc4[m][1]);
        }
    }

    // ---- Layer 5 (20->1) dot: per-lane partial ------------------------------
    v4f w5lo = *(const v4f*)(cbuf + CB_W5 + 4*g);
    v4f w5hi = *(const v4f*)(cbuf + CB_W5 + 16 + 4*g);
    float s = 0.f;
    #pragma unroll
    for (int m = 0; m < 2; ++m) {
        #pragma unroll
        for (int q = 0; q < 4; ++q) {
            float h0 = fmaxf(acc4[m][0][q], 0.f);   // bias already in acc
            float h1 = fmaxf(acc4[m][1][q], 0.f);
            s = fmaf(h0, w5lo[q], fmaf(h1, w5hi[q], s));
        }
    }
    return s;
}

// ---------------- MLP kernel: m=2 two-pass at 4 waves/SIMD -----------------
// Persistent: 256 blocks x 16 waves (1024 thr) -> 4 waves/SIMD (reg cap 128;
// r17 showed this pass compiles to 84 VGPR + AGPRs with ~0 spill). Weights +
// constants in LDS. Wave = independent worker: one batch row per iteration in
// TWO 32-e passes; sched_barrier(0) between passes keeps one pass's state
// live (r11 lesson). Spill sentinel: WRITE_SIZE.
__global__ __launch_bounds__(1024) void mlp_kernel(
    const float* __restrict__ xu, const float* __restrict__ xi,
    const float* __restrict__ b5p, const char* __restrict__ ws,
    float* __restrict__ out, int B, int NIT)
{
    __shared__ us wall[WALL_ELEMS];                // 120832 B : w3f | w2f | w4f
    __shared__ __align__(16) float cbuf[CB_ELEMS]; //   2368 B : biases + w1p

    const int tid  = (int)threadIdx.x;
    const int lane = tid & 63;
    const int wv   = __builtin_amdgcn_readfirstlane(tid >> 6);   // 0..15
    const int c = lane & 15;
    const int g = lane >> 4;
    const int wstep = (int)gridDim.x * 16;         // batch rows per iteration

    // ---- stage weights + constants to LDS once ----------------------------
    {
        const us* src = (const us*)(ws + OFF_W3F);
        for (int s = tid; s < WALL_ELEMS/8; s += 1024)
            *(v8s*)(wall + s*8) = *(const v8s*)(src + s*8);
        const float* csrc = (const float*)(ws + OFF_B2B);
        for (int s = tid; s < CB_ELEMS; s += 1024)
            cbuf[s] = csrc[s];
    }
    const us* w3l = wall;
    const us* w2l = wall + W3F_ELEMS;
    const us* w4l = wall + W3F_ELEMS + W2F_ELEMS;
    const float b5v = b5p[0];

    int b = (int)blockIdx.x*16 + wv;
    int bc = (b < B) ? b : (B - 1);
    float su = xu[(size_t)bc*64 + lane];
    float si = xi[(size_t)bc*64 + lane];
    __syncthreads();                               // weights staged (only barrier)

    #pragma unroll 1
    for (int it = 0; it < NIT; ++it) {
        const int nb = b + wstep;
        const int nbc = (nb < B) ? nb : (B - 1);
        const bool more = (it + 1 < NIT);

        // ---- pass 0 (e rows 0..31) ------------------------------------------
        v4u b1f[2];
        make_b1f2<0>(su, si, c, g, cbuf + CB_W1, b1f);
        float s = mlp_pass2(b1f, w3l, w2l, w4l, cbuf, lane, g);

        __builtin_amdgcn_sched_barrier(0);   // fence: pass-0 state dies here

        // ---- pass 1 (e rows 32..63); prefetch next x inside this region -----
        float nsu = 0.f, nsi = 0.f;
        if (more) {
            nsu = xu[(size_t)nbc*64 + lane];       // 2 coalesced loads,
            nsi = xi[(size_t)nbc*64 + lane];       // hidden under pass-1 MFMAs
        }
        make_b1f2<1>(su, si, c, g, cbuf + CB_W1, b1f);   // su/si die here
        s += mlp_pass2(b1f, w3l, w2l, w4l, cbuf, lane, g);

        __builtin_amdgcn_sched_barrier(0);   // fence: pass-1 state dies here

        // ---- mean over E=64 + sigmoid; single wave-level reduce --------------
        #pragma unroll
        for (int off = 1; off < 64; off <<= 1) s += __shfl_xor(s, off);
        if (lane == 0 && b < B)
            out[b] = 1.0f / (1.0f + expf(-(s * (1.0f / 64.0f) + b5v)));

        su = nsu; si = nsi; b = nb;
    }
}

extern "C" void kernel_launch(void* const* d_in, const int* in_sizes, int n_in,
                              void* d_out, int out_size, void* d_ws, size_t ws_size,
                              hipStream_t stream) {
    const int*   user_idxs = (const int*)d_in[0];
    const int*   item_idxs = (const int*)d_in[1];
    const int*   uidx      = (const int*)d_in[2];
    const int*   iidx      = (const int*)d_in[3];
    const float* uemb      = (const float*)d_in[4];
    const float* iemb      = (const float*)d_in[5];
    const float* w1 = (const float*)d_in[6];
    const float* b1 = (const float*)d_in[7];
    const float* w2 = (const float*)d_in[8];
    const float* b2 = (const float*)d_in[9];
    const float* w3 = (const float*)d_in[10];
    const float* b3 = (const float*)d_in[11];
    const float* w4 = (const float*)d_in[12];
    const float* b4 = (const float*)d_in[13];
    const float* w5 = (const float*)d_in[14];
    const float* b5 = (const float*)d_in[15];
    float* out = (float*)d_out;
    char* ws = (char*)d_ws;

    const int B    = in_sizes[0];
    const int nu64 = in_sizes[4];   // N_USERS * 64
    const int ni64 = in_sizes[5];   // N_ITEMS * 64

    float* xu = (float*)(ws + OFF_X);
    float* xi = xu + (size_t)B * 64;
    _Float16* ue16 = (_Float16*)(ws + OFF_X + (size_t)2 * B * 64 * 4);
    _Float16* ie16 = ue16 + nu64;

    hipLaunchKernelGGL(prep_conv_kernel, dim3(1024), dim3(256), 0, stream,
                       w1, b1, w2, w3, w4, b2, b3, b4, w5, ws,
                       uemb, iemb, ue16, ie16, nu64, ni64);

    const int ntask = 2 * B;                       // (b, table) wave-tasks
    hipLaunchKernelGGL(gather_kernel, dim3((ntask + 3) / 4), dim3(256), 0, stream,
                       user_idxs, item_idxs, uidx, iidx, ue16, ie16, xu, xi, B);

    const int GRID = 256;
    const int rows_per_iter = GRID * 16;
    const int NIT = (B + rows_per_iter - 1) / rows_per_iter;
    hipLaunchKernelGGL(mlp_kernel, dim3(GRID), dim3(1024), 0, stream,
                       xu, xi, b5, ws, out, B, NIT);
}